// Round 13
// baseline (262.962 us; speedup 1.0000x reference)
//
#include <hip/hip_runtime.h>
#include <hip/hip_bf16.h>

// GConvGRU (ChebConv K=2), fp32 in/out; bf16 MFMA GEMM; fp8 gather path.
// Zin row K-layout: [x | hx | px | ph] (512 bf16 = 1 KB/node).
// xf8[n]: 256 fp8 bytes = concat(x[n],hx[n]) UNSCALED; agg applies norm[src]
//   per-edge via pk_fma (idx 2-ahead / norm 1-ahead prefetch).
// 5 dispatches: memset -> bucket+prep+convert (blockIdx-split; bucket sharded
//   512 chunks) -> csr (lean, NPS=256) -> agg -> gemm (fused epilogue).
// GEMM: 128x128 tile (r10-verified), fused gate epilogue, dbuf LDS +
//   counted vmcnt(4).

typedef unsigned short u16;
typedef unsigned int u32;
typedef __attribute__((ext_vector_type(8))) __bf16 bf16x8;
typedef __attribute__((ext_vector_type(4))) float f32x4;
typedef __attribute__((ext_vector_type(2))) float f32x2;
typedef __attribute__((ext_vector_type(4))) int int4v;

#define F_IN 128
#define HID 128
#define NPS 256           // nodes per segment (power of 2: r = d >> 8)
#define NPS_SHIFT 8
#define MAXSEG 256        // array sizing (NSEG = 196 for N=50000)

__device__ __forceinline__ u16 f2bf(float f) {
    u32 u;
    __builtin_memcpy(&u, &f, 4);
    u = (u + 0x7fffu + ((u >> 16) & 1u)) >> 16;
    return (u16)u;
}
__device__ __forceinline__ u32 packbf(float a, float b) {
    return ((u32)f2bf(b) << 16) | (u32)f2bf(a);
}
__device__ __forceinline__ float sigmoidf_(float x) {
    return 1.0f / (1.0f + __expf(-x));
}

__device__ __forceinline__ void async_copy16(void* lds, const void* gptr) {
    __builtin_amdgcn_global_load_lds(
        (__attribute__((address_space(1))) void*)gptr,
        (__attribute__((address_space(3))) void*)lds,
        16, 0, 0);
}

// ------------- 1. bucket [0,512) + prep [512,1536) + convert [1536,...) -------------
__global__ __launch_bounds__(256) void bucket_prep_conv_kernel(
        const int* __restrict__ src, const int* __restrict__ dst, int E,
        int* __restrict__ segCount, int2* __restrict__ bedges,
        int segCap, int edgesPerChunk, int NSEG,
        const float* __restrict__ Wrx, const float* __restrict__ Wrh,
        const float* __restrict__ Wux, const float* __restrict__ Wuh,
        const float* __restrict__ Wcx, const float* __restrict__ Wch,
        const float* __restrict__ brx, const float* __restrict__ brh,
        const float* __restrict__ bux, const float* __restrict__ buh,
        const float* __restrict__ bcx, const float* __restrict__ bch,
        u16* __restrict__ WT, float* __restrict__ bias,
        const float* __restrict__ x, const float* __restrict__ hx,
        u32* __restrict__ zin, u32* __restrict__ xf8, int N) {
    if (blockIdx.x >= 1536) {
        // ---- convert role: x,hx -> zin bf16 slots + UNSCALED fp8 rows ----
        int t = (blockIdx.x - 1536) * 256 + threadIdx.x;
        if (t >= N * 64) return;
        int n = t >> 6, c4 = t & 63;
        float4 v;
        int zbase;
        if (c4 < 32) {
            v = ((const float4*)x)[n * 32 + c4];
            zbase = n * 256 + 2 * c4;
        } else {
            v = ((const float4*)hx)[n * 32 + (c4 - 32)];
            zbase = n * 256 + 64 + 2 * (c4 - 32);
        }
        zin[zbase] = packbf(v.x, v.y);
        zin[zbase + 1] = packbf(v.z, v.w);
        u32 o = 0;
        o = (u32)__builtin_amdgcn_cvt_pk_fp8_f32(v.x, v.y, (int)o, false);
        o = (u32)__builtin_amdgcn_cvt_pk_fp8_f32(v.z, v.w, (int)o, true);
        xf8[t] = o;
        return;
    }
    if (blockIdx.x >= 512) {
        // ---- prep role: WT col layout c' = (f>>4)*64 + part*16 + (f&15) ----
        int t = (blockIdx.x - 512) * 256 + threadIdx.x;  // [0, 512*512)
        int cp = t >> 9, k = t & 511;
        int fc = cp >> 6, p = (cp >> 4) & 3, cf = cp & 15;
        int f = fc * 16 + cf;                 // feature 0..127
        int kpart = k >> 7;
        int kf = k & 127;
        int t01 = (kpart & 2) ? 1 : 0;
        bool isX = !(kpart & 1);
        int wi = t01 * (128 * 128) + kf * 128 + f;
        float val = 0.0f;
        if (p == 0) val = isX ? Wrx[wi] : Wrh[wi];
        else if (p == 1) val = isX ? Wux[wi] : Wuh[wi];
        else if (p == 2) { if (isX) val = Wcx[wi]; }
        else { if (!isX) val = Wch[wi]; }
        WT[t] = f2bf(val);
        if (t < 512) {
            int bp = (t >> 4) & 3;
            int bf_ = (t >> 6) * 16 + (t & 15);
            float b = 0.0f;
            if (bp == 0) b = brx[bf_] + brh[bf_];
            else if (bp == 1) b = bux[bf_] + buh[bf_];
            else if (bp == 2) b = bcx[bf_];
            else b = bch[bf_];
            bias[t] = b;
        }
        return;
    }
    // ---- bucket role (512 chunks) ----
    __shared__ int cnt[MAXSEG], base[MAXSEG], pos[MAXSEG];
    for (int i = threadIdx.x; i < NSEG; i += 256) cnt[i] = 0;
    __syncthreads();
    int beg = blockIdx.x * edgesPerChunk;
    int end = beg + edgesPerChunk;
    if (end > E) end = E;
    // pass 1: per-segment counts
    for (int i = beg + (int)threadIdx.x * 4; i < end; i += 256 * 4) {
        if (i + 4 <= end) {
            int4v d4 = *(const int4v*)(dst + i);
#pragma unroll
            for (int j = 0; j < 4; ++j) atomicAdd(&cnt[(unsigned)d4[j] >> NPS_SHIFT], 1);
        } else {
            for (int j = i; j < end; ++j) atomicAdd(&cnt[(unsigned)dst[j] >> NPS_SHIFT], 1);
        }
    }
    __syncthreads();
    for (int i = threadIdx.x; i < NSEG; i += 256) {
        base[i] = atomicAdd(&segCount[i], cnt[i]);
        pos[i] = 0;
    }
    __syncthreads();
    // pass 2: emit (chunk is cache-hot from pass 1)
    for (int i = beg + (int)threadIdx.x * 4; i < end; i += 256 * 4) {
        if (i + 4 <= end) {
            int4v d4 = *(const int4v*)(dst + i);
            int4v s4 = *(const int4v*)(src + i);
#pragma unroll
            for (int j = 0; j < 4; ++j) {
                int d = d4[j];
                unsigned r = (unsigned)d >> NPS_SHIFT;
                int p = atomicAdd(&pos[r], 1);
                int o = base[r] + p;
                if (o < segCap) bedges[(size_t)r * segCap + o] = make_int2(d, s4[j]);
            }
        } else {
            for (int j = i; j < end; ++j) {
                int d = dst[j];
                unsigned r = (unsigned)d >> NPS_SHIFT;
                int p = atomicAdd(&pos[r], 1);
                int o = base[r] + p;
                if (o < segCap) bedges[(size_t)r * segCap + o] = make_int2(d, src[j]);
            }
        }
    }
}

// ------------- 2. per-segment CSR (lean, NPS=256): hist+scan+row_ptr+norm+fill ------
__global__ __launch_bounds__(1024) void csr_kernel(const int2* __restrict__ bedges,
                                                   const int* __restrict__ segCount,
                                                   int* __restrict__ row_ptr,
                                                   float* __restrict__ norm,
                                                   int* __restrict__ esrc,
                                                   int segCap, int N, int E, int NSEG) {
    __shared__ int hist[NPS];
    __shared__ int sseg[MAXSEG];
    __shared__ int segBaseSh;
    int seg = blockIdx.x;
    int tid = threadIdx.x;
    int lo = seg << NPS_SHIFT;
    int npr = N - lo;
    if (npr > NPS) npr = NPS;

    // mini-scan of segCount[0..NSEG) for segBase
    if (tid < MAXSEG) sseg[tid] = (tid < NSEG) ? segCount[tid] : 0;
    __syncthreads();
    for (int off = 1; off < MAXSEG; off <<= 1) {
        int v = 0;
        if (tid < MAXSEG && tid >= off) v = sseg[tid - off];
        __syncthreads();
        if (tid < MAXSEG) sseg[tid] += v;
        __syncthreads();
    }
    if (tid == 0) segBaseSh = (seg == 0) ? 0 : sseg[seg - 1];
    if (tid < NPS) hist[tid] = 0;
    __syncthreads();

    int cnt = segCount[seg];
    if (cnt > segCap) cnt = segCap;
    const int2* segp = bedges + (size_t)seg * segCap;

    // pass 1: histogram dst
    for (int i = tid; i < cnt; i += 1024) atomicAdd(&hist[segp[i].x - lo], 1);
    __syncthreads();
    int myCount = (tid < NPS) ? hist[tid] : 0;
    __syncthreads();
    // inclusive scan of hist
    for (int off = 1; off < NPS; off <<= 1) {
        int v = 0;
        if (tid < NPS && tid >= off) v = hist[tid - off];
        __syncthreads();
        if (tid < NPS) hist[tid] += v;
        __syncthreads();
    }
    int segBase = segBaseSh;
    if (tid < npr) {
        int excl = hist[tid] - myCount;
        row_ptr[lo + tid] = segBase + excl;
        norm[lo + tid] = rsqrtf((float)(myCount > 1 ? myCount : 1));
    }
    __syncthreads();
    if (tid < NPS) hist[tid] = segBase + hist[tid] - myCount;  // global cursors
    __syncthreads();
    // pass 2: fill (private window)
    for (int i = tid; i < cnt; i += 1024) {
        int2 e = segp[i];
        int slot = atomicAdd(&hist[e.x - lo], 1);
        esrc[slot] = e.y;
    }
    if (seg == NSEG - 1 && tid == 0) row_ptr[N] = E;
}

// ------------- 3. agg: wave-per-node, 8 edges/iter, idx 2-ahead / norm 1-ahead ------
__device__ __forceinline__ void accum4s(f32x2* acc, uint4 v, float ns) {
#pragma unroll
    for (int i = 0; i < 4; ++i) {
        u32 w = (i == 0) ? v.x : (i == 1) ? v.y : (i == 2) ? v.z : v.w;
        f32x2 lo = (f32x2)__builtin_amdgcn_cvt_pk_f32_fp8((int)w, false);
        f32x2 hi = (f32x2)__builtin_amdgcn_cvt_pk_f32_fp8((int)w, true);
        acc[2 * i] += lo * ns;
        acc[2 * i + 1] += hi * ns;
    }
}

__global__ __launch_bounds__(256) void agg_kernel(const int* __restrict__ row_ptr,
                                                  const int* __restrict__ esrc,
                                                  const float* __restrict__ norm,
                                                  const u32* __restrict__ xf8,
                                                  u32* __restrict__ zin, int N) {
    int node = blockIdx.x * 4 + (threadIdx.x >> 6);
    int lane = threadIdx.x & 63;
    if (node >= N) return;
    int q = lane >> 4;
    int li = lane & 15;
    int beg = row_ptr[node], end = row_ptr[node + 1];
    const uint4* z4 = (const uint4*)xf8;
    f32x2 acc[8];
#pragma unroll
    for (int i = 0; i < 8; ++i) acc[i] = (f32x2){0.f, 0.f};

    int nE = end - beg;
    int T = (nE & ~7) >> 3;   // main 8-edge iterations
    int e = beg;
    if (T > 0) {
        int s0A = esrc[e + q], s0B = esrc[e + q + 4];
        float n0A = norm[s0A], n0B = norm[s0B];
        int s1A = 0, s1B = 0;
        if (T > 1) {
            s1A = esrc[e + 8 + q];
            s1B = esrc[e + 12 + q];
        }
        for (int t = 0; t < T; ++t) {
            uint4 vA = z4[(size_t)s0A * 16 + li];
            uint4 vB = z4[(size_t)s0B * 16 + li];
            int s2A = 0, s2B = 0;
            if (t + 2 < T) {
                s2A = esrc[e + 16 + q];
                s2B = esrc[e + 20 + q];
            }
            float n1A = 0.f, n1B = 0.f;
            if (t + 1 < T) {
                n1A = norm[s1A];
                n1B = norm[s1B];
            }
            accum4s(acc, vA, n0A);
            accum4s(acc, vB, n0B);
            s0A = s1A; s0B = s1B;
            n0A = n1A; n0B = n1B;
            s1A = s2A; s1B = s2B;
            e += 8;
        }
    }
    for (int t2 = beg + T * 8 + q; t2 < end; t2 += 4) {
        int s = esrc[t2];
        float ns = norm[s];
        uint4 v = z4[(size_t)s * 16 + li];
        accum4s(acc, v, ns);
    }
#pragma unroll
    for (int i = 0; i < 8; ++i) {
        acc[i].x += __shfl_xor(acc[i].x, 16);
        acc[i].y += __shfl_xor(acc[i].y, 16);
        acc[i].x += __shfl_xor(acc[i].x, 32);
        acc[i].y += __shfl_xor(acc[i].y, 32);
    }
    if (lane < 16) {
        float nn = -norm[node];
        uint4 o0, o1;
        o0.x = packbf(acc[0].x * nn, acc[0].y * nn);
        o0.y = packbf(acc[1].x * nn, acc[1].y * nn);
        o0.z = packbf(acc[2].x * nn, acc[2].y * nn);
        o0.w = packbf(acc[3].x * nn, acc[3].y * nn);
        o1.x = packbf(acc[4].x * nn, acc[4].y * nn);
        o1.y = packbf(acc[5].x * nn, acc[5].y * nn);
        o1.z = packbf(acc[6].x * nn, acc[6].y * nn);
        o1.w = packbf(acc[7].x * nn, acc[7].y * nn);
        uint4* dst4 = (uint4*)zin + (size_t)node * 64 + 32 + li * 2;
        dst4[0] = o0;
        dst4[1] = o1;
    }
}

// ------------- 4. MFMA GEMM (128x128, dbuf + counted vmcnt) + fused epilogue -------------
__global__ __launch_bounds__(256) void gemm_fused_kernel(
        const u16* __restrict__ A, const u16* __restrict__ B,
        const float* __restrict__ bias, const float* __restrict__ hx,
        float* __restrict__ out, int N) {
    __shared__ __align__(16) __bf16 As[2][128 * 32];
    __shared__ __align__(16) __bf16 Bs[2][128 * 32];
    int tid = threadIdx.x;
    int wave = tid >> 6, lane = tid & 63;

    // bijective XCD swizzle (total = gridDim.x, not necessarily %8==0)
    int total = gridDim.x;
    int bid = blockIdx.x;
    int q = total >> 3, r = total & 7;
    int xcd = bid & 7, idx = bid >> 3;
    int wg = (xcd < r ? xcd * (q + 1) : r * (q + 1) + (xcd - r) * q) + idx;
    int m0 = (wg >> 2) * 128;
    int n0 = (wg & 3) * 128;

    int wm = wave & 1, wn = wave >> 1;
    int quad = lane >> 4, l15 = lane & 15;

    // per-wave staging geometry (2 chunks/wave, each 512 bf16 = 16 rows x 32)
    int chunk0 = wave * 2;
    int fl0 = chunk0 * 512 + lane * 8;
    int row0 = fl0 >> 5, col0 = fl0 & 31;
    int fl1 = (chunk0 + 1) * 512 + lane * 8;
    int row1 = fl1 >> 5, col1 = fl1 & 31;
    const u16* Arow0 = A + (size_t)(m0 + row0) * 512 + col0;
    const u16* Arow1 = A + (size_t)(m0 + row1) * 512 + col1;
    const u16* Brow0 = B + (size_t)(n0 + row0) * 512 + col0;
    const u16* Brow1 = B + (size_t)(n0 + row1) * 512 + col1;

    f32x4 acc[4][4];
#pragma unroll
    for (int mi = 0; mi < 4; ++mi)
#pragma unroll
        for (int ni = 0; ni < 4; ++ni) acc[mi][ni] = (f32x4){0.f, 0.f, 0.f, 0.f};

    // prologue: stage tile 0 into buf 0 (4 loads/wave in flight)
    async_copy16(&As[0][fl0], Arow0);
    async_copy16(&As[0][fl1], Arow1);
    async_copy16(&Bs[0][fl0], Brow0);
    async_copy16(&Bs[0][fl1], Brow1);

    int cur = 0;
    for (int t = 0; t < 16; ++t) {
        if (t < 15) {
            int k1 = (t + 1) * 32;
            async_copy16(&As[cur ^ 1][fl0], Arow0 + k1);
            async_copy16(&As[cur ^ 1][fl1], Arow1 + k1);
            async_copy16(&Bs[cur ^ 1][fl0], Brow0 + k1);
            async_copy16(&Bs[cur ^ 1][fl1], Brow1 + k1);
            // wait for tile t's 4 loads; tile t+1's 4 remain in flight
            asm volatile("s_waitcnt vmcnt(4)" ::: "memory");
        } else {
            asm volatile("s_waitcnt vmcnt(0)" ::: "memory");
        }
        __builtin_amdgcn_s_barrier();

        bf16x8 af[4], bfr[4];
#pragma unroll
        for (int mi = 0; mi < 4; ++mi)
            af[mi] = *(const bf16x8*)&As[cur][(wm * 64 + mi * 16 + l15) * 32 + quad * 8];
#pragma unroll
        for (int ni = 0; ni < 4; ++ni)
            bfr[ni] = *(const bf16x8*)&Bs[cur][(wn * 64 + ni * 16 + l15) * 32 + quad * 8];
#pragma unroll
        for (int mi = 0; mi < 4; ++mi)
#pragma unroll
            for (int ni = 0; ni < 4; ++ni)
                acc[mi][ni] = __builtin_amdgcn_mfma_f32_16x16x32_bf16(af[mi], bfr[ni],
                                                                      acc[mi][ni], 0, 0, 0);
        // this wave's ds_reads are consumed; fence the buffer swap
        asm volatile("s_waitcnt lgkmcnt(0)" ::: "memory");
        __builtin_amdgcn_s_barrier();
        cur ^= 1;
    }

    // fused epilogue: part = ni, feature f = ((n0>>6)+wn)*16 + l15
    int f = ((n0 >> 6) + wn) * 16 + l15;
    int cbase = ((n0 >> 6) + wn) * 64 + l15;
    float bR = bias[cbase + 0];
    float bU = bias[cbase + 16];
    float bX = bias[cbase + 32];
    float bH = bias[cbase + 48];
#pragma unroll
    for (int mi = 0; mi < 4; ++mi) {
        f32x4 aR = acc[mi][0];
        f32x4 aU = acc[mi][1];
        f32x4 aX = acc[mi][2];
        f32x4 aH = acc[mi][3];
#pragma unroll
        for (int r2 = 0; r2 < 4; ++r2) {
            int row = m0 + wm * 64 + mi * 16 + quad * 4 + r2;
            if (row < N) {
                float h = hx[(size_t)row * 128 + f];
                float rr = sigmoidf_(aR[r2] + bR);
                float uu = sigmoidf_(aU[r2] + bU);
                float cc = sigmoidf_((aX[r2] + bX) + (aH[r2] + bH) * rr);
                out[(size_t)row * 128 + f] = uu * h + (1.0f - uu) * cc;
            }
        }
    }
}

extern "C" void kernel_launch(void* const* d_in, const int* in_sizes, int n_in,
                              void* d_out, int out_size, void* d_ws, size_t ws_size,
                              hipStream_t stream) {
    const int* ei = (const int*)d_in[0];
    int E = in_sizes[0] / 2;
    const float* x = (const float*)d_in[1];
    const float* hx = (const float*)d_in[2];
    int N = in_sizes[1] / F_IN;
    const float* Wrx = (const float*)d_in[3];
    const float* brx = (const float*)d_in[4];
    const float* Wrh = (const float*)d_in[5];
    const float* brh = (const float*)d_in[6];
    const float* Wux = (const float*)d_in[7];
    const float* bux = (const float*)d_in[8];
    const float* Wuh = (const float*)d_in[9];
    const float* buh = (const float*)d_in[10];
    const float* Wcx = (const float*)d_in[11];
    const float* bcx = (const float*)d_in[12];
    const float* Wch = (const float*)d_in[13];
    const float* bch = (const float*)d_in[14];

    int Mpad = ((N + 127) / 128) * 128;
    int NSEG = (N + NPS - 1) / NPS;          // 196 for N=50000
    int segCap = E / NSEG + 2048;

    char* ws = (char*)d_ws;
    size_t off = 0;
    auto alloc = [&](size_t bytes) {
        size_t o = off;
        off = (off + bytes + 255) & ~(size_t)255;
        return o;
    };
    int* segCount = (int*)(ws + alloc(1024));
    int* row_ptr = (int*)(ws + alloc((size_t)(N + 1) * 4));
    float* norm = (float*)(ws + alloc((size_t)N * 4));
    int* esrc = (int*)(ws + alloc((size_t)E * 4));
    int2* bedges = (int2*)(ws + alloc((size_t)NSEG * segCap * 8));
    u16* WT = (u16*)(ws + alloc((size_t)512 * 512 * 2));
    float* bias = (float*)(ws + alloc((size_t)512 * 4));
    u32* xf8 = (u32*)(ws + alloc((size_t)N * 64 * 4));
    u16* Zin = (u16*)(ws + alloc((size_t)Mpad * 512 * 2));
    (void)ws_size;

    hipMemsetAsync(segCount, 0, 1024, stream);
    {
        const int bChunks = 512;
        int epc = (((E + bChunks - 1) / bChunks) + 3) & ~3;
        int convBlocks = (N * 64 + 255) / 256;
        bucket_prep_conv_kernel<<<1536 + convBlocks, 256, 0, stream>>>(
            ei, ei + E, E, segCount, bedges, segCap, epc, NSEG,
            Wrx, Wrh, Wux, Wuh, Wcx, Wch,
            brx, brh, bux, buh, bcx, bch, WT, bias,
            x, hx, (u32*)Zin, xf8, N);
    }
    csr_kernel<<<NSEG, 1024, 0, stream>>>(bedges, segCount, row_ptr, norm, esrc,
                                          segCap, N, E, NSEG);
    agg_kernel<<<(N + 3) / 4, 256, 0, stream>>>(row_ptr, esrc, norm, xf8, (u32*)Zin, N);
    gemm_fused_kernel<<<dim3((Mpad / 128) * 4), 256, 0, stream>>>(Zin, WT, bias, hx,
                                                                  (float*)d_out, N);
}

// Round 14
// 250.951 us; speedup vs baseline: 1.0479x; 1.0479x over previous
//
#include <hip/hip_runtime.h>
#include <hip/hip_bf16.h>

// GConvGRU (ChebConv K=2), fp32 in/out; bf16 MFMA GEMM; fp8 gather path.
// Zin row K-layout: [x | hx | px | ph] (512 bf16 = 1 KB/node).
// xf8[n]: 256 fp8 bytes = concat(x[n],hx[n]) UNSCALED; agg applies norm[src]
//   per-edge via pk_fma (idx 2-ahead / norm 1-ahead prefetch).
// 5 dispatches: memset -> bucket+prep+convert (blockIdx-split) -> csr (lean,
//   NPS=256 -> 196 blocks) -> agg -> gemm (fused epilogue).
// GEMM: 128x128 tile, fused gate epilogue, dbuf LDS + counted vmcnt(4).
// This is the round-10 verified best configuration (251.5 us).

typedef unsigned short u16;
typedef unsigned int u32;
typedef __attribute__((ext_vector_type(8))) __bf16 bf16x8;
typedef __attribute__((ext_vector_type(4))) float f32x4;
typedef __attribute__((ext_vector_type(2))) float f32x2;
typedef __attribute__((ext_vector_type(4))) int int4v;

#define F_IN 128
#define HID 128
#define NPS 256           // nodes per segment (power of 2: r = d >> 8)
#define NPS_SHIFT 8
#define MAXSEG 256        // array sizing (NSEG = 196 for N=50000)

__device__ __forceinline__ u16 f2bf(float f) {
    u32 u;
    __builtin_memcpy(&u, &f, 4);
    u = (u + 0x7fffu + ((u >> 16) & 1u)) >> 16;
    return (u16)u;
}
__device__ __forceinline__ u32 packbf(float a, float b) {
    return ((u32)f2bf(b) << 16) | (u32)f2bf(a);
}
__device__ __forceinline__ float sigmoidf_(float x) {
    return 1.0f / (1.0f + __expf(-x));
}

__device__ __forceinline__ void async_copy16(void* lds, const void* gptr) {
    __builtin_amdgcn_global_load_lds(
        (__attribute__((address_space(1))) void*)gptr,
        (__attribute__((address_space(3))) void*)lds,
        16, 0, 0);
}

// ------------- 1. bucket [0,256) + prep [256,1280) + convert [1280,...) -------------
__global__ __launch_bounds__(256) void bucket_prep_conv_kernel(
        const int* __restrict__ src, const int* __restrict__ dst, int E,
        int* __restrict__ segCount, int2* __restrict__ bedges,
        int segCap, int edgesPerChunk, int NSEG,
        const float* __restrict__ Wrx, const float* __restrict__ Wrh,
        const float* __restrict__ Wux, const float* __restrict__ Wuh,
        const float* __restrict__ Wcx, const float* __restrict__ Wch,
        const float* __restrict__ brx, const float* __restrict__ brh,
        const float* __restrict__ bux, const float* __restrict__ buh,
        const float* __restrict__ bcx, const float* __restrict__ bch,
        u16* __restrict__ WT, float* __restrict__ bias,
        const float* __restrict__ x, const float* __restrict__ hx,
        u32* __restrict__ zin, u32* __restrict__ xf8, int N) {
    if (blockIdx.x >= 1280) {
        // ---- convert role: x,hx -> zin bf16 slots + UNSCALED fp8 rows ----
        int t = (blockIdx.x - 1280) * 256 + threadIdx.x;
        if (t >= N * 64) return;
        int n = t >> 6, c4 = t & 63;
        float4 v;
        int zbase;
        if (c4 < 32) {
            v = ((const float4*)x)[n * 32 + c4];
            zbase = n * 256 + 2 * c4;
        } else {
            v = ((const float4*)hx)[n * 32 + (c4 - 32)];
            zbase = n * 256 + 64 + 2 * (c4 - 32);
        }
        zin[zbase] = packbf(v.x, v.y);
        zin[zbase + 1] = packbf(v.z, v.w);
        u32 o = 0;
        o = (u32)__builtin_amdgcn_cvt_pk_fp8_f32(v.x, v.y, (int)o, false);
        o = (u32)__builtin_amdgcn_cvt_pk_fp8_f32(v.z, v.w, (int)o, true);
        xf8[t] = o;
        return;
    }
    if (blockIdx.x >= 256) {
        // ---- prep role: WT col layout c' = (f>>4)*64 + part*16 + (f&15) ----
        int t = (blockIdx.x - 256) * 256 + threadIdx.x;  // [0, 512*512)
        int cp = t >> 9, k = t & 511;
        int fc = cp >> 6, p = (cp >> 4) & 3, cf = cp & 15;
        int f = fc * 16 + cf;                 // feature 0..127
        int kpart = k >> 7;
        int kf = k & 127;
        int t01 = (kpart & 2) ? 1 : 0;
        bool isX = !(kpart & 1);
        int wi = t01 * (128 * 128) + kf * 128 + f;
        float val = 0.0f;
        if (p == 0) val = isX ? Wrx[wi] : Wrh[wi];
        else if (p == 1) val = isX ? Wux[wi] : Wuh[wi];
        else if (p == 2) { if (isX) val = Wcx[wi]; }
        else { if (!isX) val = Wch[wi]; }
        WT[t] = f2bf(val);
        if (t < 512) {
            int bp = (t >> 4) & 3;
            int bf_ = (t >> 6) * 16 + (t & 15);
            float b = 0.0f;
            if (bp == 0) b = brx[bf_] + brh[bf_];
            else if (bp == 1) b = bux[bf_] + buh[bf_];
            else if (bp == 2) b = bcx[bf_];
            else b = bch[bf_];
            bias[t] = b;
        }
        return;
    }
    // ---- bucket role ----
    __shared__ int cnt[MAXSEG], base[MAXSEG], pos[MAXSEG];
    for (int i = threadIdx.x; i < NSEG; i += 256) cnt[i] = 0;
    __syncthreads();
    int beg = blockIdx.x * edgesPerChunk;
    int end = beg + edgesPerChunk;
    if (end > E) end = E;
    // pass 1: per-segment counts
    for (int i = beg + (int)threadIdx.x * 4; i < end; i += 256 * 4) {
        if (i + 4 <= end) {
            int4v d4 = *(const int4v*)(dst + i);
#pragma unroll
            for (int j = 0; j < 4; ++j) atomicAdd(&cnt[(unsigned)d4[j] >> NPS_SHIFT], 1);
        } else {
            for (int j = i; j < end; ++j) atomicAdd(&cnt[(unsigned)dst[j] >> NPS_SHIFT], 1);
        }
    }
    __syncthreads();
    for (int i = threadIdx.x; i < NSEG; i += 256) {
        base[i] = atomicAdd(&segCount[i], cnt[i]);
        pos[i] = 0;
    }
    __syncthreads();
    // pass 2: emit (chunk is cache-hot from pass 1)
    for (int i = beg + (int)threadIdx.x * 4; i < end; i += 256 * 4) {
        if (i + 4 <= end) {
            int4v d4 = *(const int4v*)(dst + i);
            int4v s4 = *(const int4v*)(src + i);
#pragma unroll
            for (int j = 0; j < 4; ++j) {
                int d = d4[j];
                unsigned r = (unsigned)d >> NPS_SHIFT;
                int p = atomicAdd(&pos[r], 1);
                int o = base[r] + p;
                if (o < segCap) bedges[(size_t)r * segCap + o] = make_int2(d, s4[j]);
            }
        } else {
            for (int j = i; j < end; ++j) {
                int d = dst[j];
                unsigned r = (unsigned)d >> NPS_SHIFT;
                int p = atomicAdd(&pos[r], 1);
                int o = base[r] + p;
                if (o < segCap) bedges[(size_t)r * segCap + o] = make_int2(d, src[j]);
            }
        }
    }
}

// ------------- 2. per-segment CSR (lean, NPS=256): hist+scan+row_ptr+norm+fill ------
__global__ __launch_bounds__(1024) void csr_kernel(const int2* __restrict__ bedges,
                                                   const int* __restrict__ segCount,
                                                   int* __restrict__ row_ptr,
                                                   float* __restrict__ norm,
                                                   int* __restrict__ esrc,
                                                   int segCap, int N, int E, int NSEG) {
    __shared__ int hist[NPS];
    __shared__ int sseg[MAXSEG];
    __shared__ int segBaseSh;
    int seg = blockIdx.x;
    int tid = threadIdx.x;
    int lo = seg << NPS_SHIFT;
    int npr = N - lo;
    if (npr > NPS) npr = NPS;

    // mini-scan of segCount[0..NSEG) for segBase
    if (tid < MAXSEG) sseg[tid] = (tid < NSEG) ? segCount[tid] : 0;
    __syncthreads();
    for (int off = 1; off < MAXSEG; off <<= 1) {
        int v = 0;
        if (tid < MAXSEG && tid >= off) v = sseg[tid - off];
        __syncthreads();
        if (tid < MAXSEG) sseg[tid] += v;
        __syncthreads();
    }
    if (tid == 0) segBaseSh = (seg == 0) ? 0 : sseg[seg - 1];
    if (tid < NPS) hist[tid] = 0;
    __syncthreads();

    int cnt = segCount[seg];
    if (cnt > segCap) cnt = segCap;
    const int2* segp = bedges + (size_t)seg * segCap;

    // pass 1: histogram dst
    for (int i = tid; i < cnt; i += 1024) atomicAdd(&hist[segp[i].x - lo], 1);
    __syncthreads();
    int myCount = (tid < NPS) ? hist[tid] : 0;
    __syncthreads();
    // inclusive scan of hist
    for (int off = 1; off < NPS; off <<= 1) {
        int v = 0;
        if (tid < NPS && tid >= off) v = hist[tid - off];
        __syncthreads();
        if (tid < NPS) hist[tid] += v;
        __syncthreads();
    }
    int segBase = segBaseSh;
    if (tid < npr) {
        int excl = hist[tid] - myCount;
        row_ptr[lo + tid] = segBase + excl;
        norm[lo + tid] = rsqrtf((float)(myCount > 1 ? myCount : 1));
    }
    __syncthreads();
    if (tid < NPS) hist[tid] = segBase + hist[tid] - myCount;  // global cursors
    __syncthreads();
    // pass 2: fill (private window)
    for (int i = tid; i < cnt; i += 1024) {
        int2 e = segp[i];
        int slot = atomicAdd(&hist[e.x - lo], 1);
        esrc[slot] = e.y;
    }
    if (seg == NSEG - 1 && tid == 0) row_ptr[N] = E;
}

// ------------- 3. agg: wave-per-node, 8 edges/iter, idx 2-ahead / norm 1-ahead ------
__device__ __forceinline__ void accum4s(f32x2* acc, uint4 v, float ns) {
#pragma unroll
    for (int i = 0; i < 4; ++i) {
        u32 w = (i == 0) ? v.x : (i == 1) ? v.y : (i == 2) ? v.z : v.w;
        f32x2 lo = (f32x2)__builtin_amdgcn_cvt_pk_f32_fp8((int)w, false);
        f32x2 hi = (f32x2)__builtin_amdgcn_cvt_pk_f32_fp8((int)w, true);
        acc[2 * i] += lo * ns;
        acc[2 * i + 1] += hi * ns;
    }
}

__global__ __launch_bounds__(256) void agg_kernel(const int* __restrict__ row_ptr,
                                                  const int* __restrict__ esrc,
                                                  const float* __restrict__ norm,
                                                  const u32* __restrict__ xf8,
                                                  u32* __restrict__ zin, int N) {
    int node = blockIdx.x * 4 + (threadIdx.x >> 6);
    int lane = threadIdx.x & 63;
    if (node >= N) return;
    int q = lane >> 4;
    int li = lane & 15;
    int beg = row_ptr[node], end = row_ptr[node + 1];
    const uint4* z4 = (const uint4*)xf8;
    f32x2 acc[8];
#pragma unroll
    for (int i = 0; i < 8; ++i) acc[i] = (f32x2){0.f, 0.f};

    int nE = end - beg;
    int T = (nE & ~7) >> 3;   // main 8-edge iterations
    int e = beg;
    if (T > 0) {
        int s0A = esrc[e + q], s0B = esrc[e + q + 4];
        float n0A = norm[s0A], n0B = norm[s0B];
        int s1A = 0, s1B = 0;
        if (T > 1) {
            s1A = esrc[e + 8 + q];
            s1B = esrc[e + 12 + q];
        }
        for (int t = 0; t < T; ++t) {
            uint4 vA = z4[(size_t)s0A * 16 + li];
            uint4 vB = z4[(size_t)s0B * 16 + li];
            int s2A = 0, s2B = 0;
            if (t + 2 < T) {
                s2A = esrc[e + 16 + q];
                s2B = esrc[e + 20 + q];
            }
            float n1A = 0.f, n1B = 0.f;
            if (t + 1 < T) {
                n1A = norm[s1A];
                n1B = norm[s1B];
            }
            accum4s(acc, vA, n0A);
            accum4s(acc, vB, n0B);
            s0A = s1A; s0B = s1B;
            n0A = n1A; n0B = n1B;
            s1A = s2A; s1B = s2B;
            e += 8;
        }
    }
    for (int t2 = beg + T * 8 + q; t2 < end; t2 += 4) {
        int s = esrc[t2];
        float ns = norm[s];
        uint4 v = z4[(size_t)s * 16 + li];
        accum4s(acc, v, ns);
    }
#pragma unroll
    for (int i = 0; i < 8; ++i) {
        acc[i].x += __shfl_xor(acc[i].x, 16);
        acc[i].y += __shfl_xor(acc[i].y, 16);
        acc[i].x += __shfl_xor(acc[i].x, 32);
        acc[i].y += __shfl_xor(acc[i].y, 32);
    }
    if (lane < 16) {
        float nn = -norm[node];
        uint4 o0, o1;
        o0.x = packbf(acc[0].x * nn, acc[0].y * nn);
        o0.y = packbf(acc[1].x * nn, acc[1].y * nn);
        o0.z = packbf(acc[2].x * nn, acc[2].y * nn);
        o0.w = packbf(acc[3].x * nn, acc[3].y * nn);
        o1.x = packbf(acc[4].x * nn, acc[4].y * nn);
        o1.y = packbf(acc[5].x * nn, acc[5].y * nn);
        o1.z = packbf(acc[6].x * nn, acc[6].y * nn);
        o1.w = packbf(acc[7].x * nn, acc[7].y * nn);
        uint4* dst4 = (uint4*)zin + (size_t)node * 64 + 32 + li * 2;
        dst4[0] = o0;
        dst4[1] = o1;
    }
}

// ------------- 4. MFMA GEMM (128x128, dbuf + counted vmcnt) + fused epilogue -------------
__global__ __launch_bounds__(256) void gemm_fused_kernel(
        const u16* __restrict__ A, const u16* __restrict__ B,
        const float* __restrict__ bias, const float* __restrict__ hx,
        float* __restrict__ out, int N) {
    __shared__ __align__(16) __bf16 As[2][128 * 32];
    __shared__ __align__(16) __bf16 Bs[2][128 * 32];
    int tid = threadIdx.x;
    int wave = tid >> 6, lane = tid & 63;

    // bijective XCD swizzle (total = gridDim.x, not necessarily %8==0)
    int total = gridDim.x;
    int bid = blockIdx.x;
    int q = total >> 3, r = total & 7;
    int xcd = bid & 7, idx = bid >> 3;
    int wg = (xcd < r ? xcd * (q + 1) : r * (q + 1) + (xcd - r) * q) + idx;
    int m0 = (wg >> 2) * 128;
    int n0 = (wg & 3) * 128;

    int wm = wave & 1, wn = wave >> 1;
    int quad = lane >> 4, l15 = lane & 15;

    // per-wave staging geometry (2 chunks/wave, each 512 bf16 = 16 rows x 32)
    int chunk0 = wave * 2;
    int fl0 = chunk0 * 512 + lane * 8;
    int row0 = fl0 >> 5, col0 = fl0 & 31;
    int fl1 = (chunk0 + 1) * 512 + lane * 8;
    int row1 = fl1 >> 5, col1 = fl1 & 31;
    const u16* Arow0 = A + (size_t)(m0 + row0) * 512 + col0;
    const u16* Arow1 = A + (size_t)(m0 + row1) * 512 + col1;
    const u16* Brow0 = B + (size_t)(n0 + row0) * 512 + col0;
    const u16* Brow1 = B + (size_t)(n0 + row1) * 512 + col1;

    f32x4 acc[4][4];
#pragma unroll
    for (int mi = 0; mi < 4; ++mi)
#pragma unroll
        for (int ni = 0; ni < 4; ++ni) acc[mi][ni] = (f32x4){0.f, 0.f, 0.f, 0.f};

    // prologue: stage tile 0 into buf 0 (4 loads/wave in flight)
    async_copy16(&As[0][fl0], Arow0);
    async_copy16(&As[0][fl1], Arow1);
    async_copy16(&Bs[0][fl0], Brow0);
    async_copy16(&Bs[0][fl1], Brow1);

    int cur = 0;
    for (int t = 0; t < 16; ++t) {
        if (t < 15) {
            int k1 = (t + 1) * 32;
            async_copy16(&As[cur ^ 1][fl0], Arow0 + k1);
            async_copy16(&As[cur ^ 1][fl1], Arow1 + k1);
            async_copy16(&Bs[cur ^ 1][fl0], Brow0 + k1);
            async_copy16(&Bs[cur ^ 1][fl1], Brow1 + k1);
            // wait for tile t's 4 loads; tile t+1's 4 remain in flight
            asm volatile("s_waitcnt vmcnt(4)" ::: "memory");
        } else {
            asm volatile("s_waitcnt vmcnt(0)" ::: "memory");
        }
        __builtin_amdgcn_s_barrier();

        bf16x8 af[4], bfr[4];
#pragma unroll
        for (int mi = 0; mi < 4; ++mi)
            af[mi] = *(const bf16x8*)&As[cur][(wm * 64 + mi * 16 + l15) * 32 + quad * 8];
#pragma unroll
        for (int ni = 0; ni < 4; ++ni)
            bfr[ni] = *(const bf16x8*)&Bs[cur][(wn * 64 + ni * 16 + l15) * 32 + quad * 8];
#pragma unroll
        for (int mi = 0; mi < 4; ++mi)
#pragma unroll
            for (int ni = 0; ni < 4; ++ni)
                acc[mi][ni] = __builtin_amdgcn_mfma_f32_16x16x32_bf16(af[mi], bfr[ni],
                                                                      acc[mi][ni], 0, 0, 0);
        // this wave's ds_reads are consumed; fence the buffer swap
        asm volatile("s_waitcnt lgkmcnt(0)" ::: "memory");
        __builtin_amdgcn_s_barrier();
        cur ^= 1;
    }

    // fused epilogue: part = ni, feature f = ((n0>>6)+wn)*16 + l15
    int f = ((n0 >> 6) + wn) * 16 + l15;
    int cbase = ((n0 >> 6) + wn) * 64 + l15;
    float bR = bias[cbase + 0];
    float bU = bias[cbase + 16];
    float bX = bias[cbase + 32];
    float bH = bias[cbase + 48];
#pragma unroll
    for (int mi = 0; mi < 4; ++mi) {
        f32x4 aR = acc[mi][0];
        f32x4 aU = acc[mi][1];
        f32x4 aX = acc[mi][2];
        f32x4 aH = acc[mi][3];
#pragma unroll
        for (int r2 = 0; r2 < 4; ++r2) {
            int row = m0 + wm * 64 + mi * 16 + quad * 4 + r2;
            if (row < N) {
                float h = hx[(size_t)row * 128 + f];
                float rr = sigmoidf_(aR[r2] + bR);
                float uu = sigmoidf_(aU[r2] + bU);
                float cc = sigmoidf_((aX[r2] + bX) + (aH[r2] + bH) * rr);
                out[(size_t)row * 128 + f] = uu * h + (1.0f - uu) * cc;
            }
        }
    }
}

extern "C" void kernel_launch(void* const* d_in, const int* in_sizes, int n_in,
                              void* d_out, int out_size, void* d_ws, size_t ws_size,
                              hipStream_t stream) {
    const int* ei = (const int*)d_in[0];
    int E = in_sizes[0] / 2;
    const float* x = (const float*)d_in[1];
    const float* hx = (const float*)d_in[2];
    int N = in_sizes[1] / F_IN;
    const float* Wrx = (const float*)d_in[3];
    const float* brx = (const float*)d_in[4];
    const float* Wrh = (const float*)d_in[5];
    const float* brh = (const float*)d_in[6];
    const float* Wux = (const float*)d_in[7];
    const float* bux = (const float*)d_in[8];
    const float* Wuh = (const float*)d_in[9];
    const float* buh = (const float*)d_in[10];
    const float* Wcx = (const float*)d_in[11];
    const float* bcx = (const float*)d_in[12];
    const float* Wch = (const float*)d_in[13];
    const float* bch = (const float*)d_in[14];

    int Mpad = ((N + 127) / 128) * 128;
    int NSEG = (N + NPS - 1) / NPS;          // 196 for N=50000
    int segCap = E / NSEG + 2048;

    char* ws = (char*)d_ws;
    size_t off = 0;
    auto alloc = [&](size_t bytes) {
        size_t o = off;
        off = (off + bytes + 255) & ~(size_t)255;
        return o;
    };
    int* segCount = (int*)(ws + alloc(1024));
    int* row_ptr = (int*)(ws + alloc((size_t)(N + 1) * 4));
    float* norm = (float*)(ws + alloc((size_t)N * 4));
    int* esrc = (int*)(ws + alloc((size_t)E * 4));
    int2* bedges = (int2*)(ws + alloc((size_t)NSEG * segCap * 8));
    u16* WT = (u16*)(ws + alloc((size_t)512 * 512 * 2));
    float* bias = (float*)(ws + alloc((size_t)512 * 4));
    u32* xf8 = (u32*)(ws + alloc((size_t)N * 64 * 4));
    u16* Zin = (u16*)(ws + alloc((size_t)Mpad * 512 * 2));
    (void)ws_size;

    hipMemsetAsync(segCount, 0, 1024, stream);
    {
        const int bChunks = 256;
        int epc = (((E + bChunks - 1) / bChunks) + 3) & ~3;
        int convBlocks = (N * 64 + 255) / 256;
        bucket_prep_conv_kernel<<<1280 + convBlocks, 256, 0, stream>>>(
            ei, ei + E, E, segCount, bedges, segCap, epc, NSEG,
            Wrx, Wrh, Wux, Wuh, Wcx, Wch,
            brx, brh, bux, buh, bcx, bch, WT, bias,
            x, hx, (u32*)Zin, xf8, N);
    }
    csr_kernel<<<NSEG, 1024, 0, stream>>>(bedges, segCount, row_ptr, norm, esrc,
                                          segCap, N, E, NSEG);
    agg_kernel<<<(N + 3) / 4, 256, 0, stream>>>(row_ptr, esrc, norm, xf8, (u32*)Zin, N);
    gemm_fused_kernel<<<dim3((Mpad / 128) * 4), 256, 0, stream>>>(Zin, WT, bias, hx,
                                                                  (float*)d_out, N);
}